// Round 1
// baseline (254.870 us; speedup 1.0000x reference)
//
#include <hip/hip_runtime.h>
#include <hip/hip_bf16.h>
#include <stdint.h>
#include <stddef.h>

typedef __attribute__((ext_vector_type(8))) short short8;
typedef __attribute__((ext_vector_type(4))) float f32x4;
typedef __attribute__((ext_vector_type(8))) unsigned short ushort8;

// ---------------------------------------------------------------------------
// global -> LDS direct copy, 16B per lane. LDS dest must be base + lane*16.
__device__ __forceinline__ void gload16(const void* g, void* l) {
    __builtin_amdgcn_global_load_lds(
        (__attribute__((address_space(1))) void*)g,
        (__attribute__((address_space(3))) void*)l,
        16, 0, 0);
}

// ---------------------------------------------------------------------------
// Pass 1: per-block partial sums of |w|. 2048 blocks x 256 threads x 32 elems.
__global__ void absmean_partial_k(const float* __restrict__ w,
                                  double* __restrict__ partials) {
    int tid = threadIdx.x;
    size_t base = (size_t)blockIdx.x * 8192 + (size_t)tid * 4;
    float s = 0.f;
#pragma unroll
    for (int i = 0; i < 8; ++i) {
        f32x4 v = *reinterpret_cast<const f32x4*>(w + base + (size_t)i * 1024);
        s += __builtin_fabsf(v.x) + __builtin_fabsf(v.y) +
             __builtin_fabsf(v.z) + __builtin_fabsf(v.w);
    }
    double d = (double)s;
#pragma unroll
    for (int off = 32; off > 0; off >>= 1) d += __shfl_down(d, off, 64);
    __shared__ double red[4];
    int lane = tid & 63, wid = tid >> 6;
    if (lane == 0) red[wid] = d;
    __syncthreads();
    if (tid == 0) partials[blockIdx.x] = red[0] + red[1] + red[2] + red[3];
}

// Pass 2: reduce partials deterministically, emit scale and scale+eps.
__global__ void absmean_final_k(const double* __restrict__ partials,
                                float* __restrict__ sc, int nparts, int count) {
    int tid = threadIdx.x;
    double d = 0.0;
    for (int i = tid; i < nparts; i += 256) d += partials[i];
#pragma unroll
    for (int off = 32; off > 0; off >>= 1) d += __shfl_down(d, off, 64);
    __shared__ double red[4];
    int lane = tid & 63, wid = tid >> 6;
    if (lane == 0) red[wid] = d;
    __syncthreads();
    if (tid == 0) {
        double total = red[0] + red[1] + red[2] + red[3];
        float scale = (float)(total / (double)count);
        sc[0] = scale;
        sc[1] = scale + 1e-8f;
    }
}

// ---------------------------------------------------------------------------
// Quantize w -> ternary bf16 (exact values -1/0/+1). 8 elems/thread.
__global__ void quantize_w_k(const float* __restrict__ w,
                             __hip_bfloat16* __restrict__ wq,
                             const float* __restrict__ sc) {
    float speps = sc[1];
    size_t i = ((size_t)blockIdx.x * 256 + threadIdx.x) * 8;
    f32x4 a = *reinterpret_cast<const f32x4*>(w + i);
    f32x4 b = *reinterpret_cast<const f32x4*>(w + i + 4);
    float v[8] = {a.x, a.y, a.z, a.w, b.x, b.y, b.z, b.w};
    ushort8 o;
#pragma unroll
    for (int j = 0; j < 8; ++j) {
        float t = v[j] / speps;                    // IEEE divide, matches ref
        t = fminf(fmaxf(t, -1.f), 1.f);
        float r = rintf(t);                        // RNE == jnp.round
        __hip_bfloat16 h = __float2bfloat16(r);    // exact for {-1,0,1}
        o[j] = *reinterpret_cast<unsigned short*>(&h);
    }
    *reinterpret_cast<ushort8*>(wq + i) = o;
}

// Cast x -> bf16 (RNE). 8 elems/thread.
__global__ void cast_x_k(const float* __restrict__ x,
                         __hip_bfloat16* __restrict__ xb) {
    size_t i = ((size_t)blockIdx.x * 256 + threadIdx.x) * 8;
    f32x4 a = *reinterpret_cast<const f32x4*>(x + i);
    f32x4 b = *reinterpret_cast<const f32x4*>(x + i + 4);
    float v[8] = {a.x, a.y, a.z, a.w, b.x, b.y, b.z, b.w};
    ushort8 o;
#pragma unroll
    for (int j = 0; j < 8; ++j) {
        __hip_bfloat16 h = __float2bfloat16(v[j]);
        o[j] = *reinterpret_cast<unsigned short*>(&h);
    }
    *reinterpret_cast<ushort8*>(xb + i) = o;
}

// ---------------------------------------------------------------------------
// m97-structure GEMM: C[M][N] = A[M][K] * B[N][K]^T, bf16 in, f32 out, *scale.
// 128x128 tile, BK=32, 256 threads (4 waves, 2x2 of 64x64 each),
// mfma_f32_16x16x32_bf16, global_load_lds width-16 staging.
__global__ __launch_bounds__(256) void gemm_bt_k(
    const __hip_bfloat16* __restrict__ A,   // [M][K]
    const __hip_bfloat16* __restrict__ B,   // [N][K]
    float* __restrict__ C,                  // [M][N]
    const float* __restrict__ sc, int M, int N, int K) {
    __shared__ __hip_bfloat16 As[128 * 32];  // 8 KiB
    __shared__ __hip_bfloat16 Bs[128 * 32];  // 8 KiB

    // bijective XCD swizzle (grid = 1024, divisible by 8)
    int nwg = gridDim.x;
    int wg = blockIdx.x;
    int swz = wg;
    if ((nwg & 7) == 0) {
        int cpx = nwg >> 3;
        swz = (wg & 7) * cpx + (wg >> 3);
    }
    int nbn = N / 128;
    int brow = (swz / nbn) * 128;
    int bcol = (swz % nbn) * 128;

    int tid = threadIdx.x;
    int lane = tid & 63;
    int wm = (tid >> 7) & 1;   // wave row (2x2 wave grid)
    int wn = (tid >> 6) & 1;   // wave col

    f32x4 acc[4][4];
#pragma unroll
    for (int m = 0; m < 4; ++m)
#pragma unroll
        for (int n = 0; n < 4; ++n) acc[m][n] = (f32x4)(0.f);

    // staging: tile row = tid>>2 (+64 for issue 1), 16B chunk = tid&3
    int srow = tid >> 2;
    int scg = tid & 3;
    const __hip_bfloat16* aSrc = A + (size_t)(brow + srow) * K + scg * 8;
    const __hip_bfloat16* bSrc = B + (size_t)(bcol + srow) * K + scg * 8;
    size_t rstride64 = (size_t)64 * K;
    char* aDst0 = (char*)As + tid * 16;
    char* aDst1 = (char*)As + (tid + 256) * 16;
    char* bDst0 = (char*)Bs + tid * 16;
    char* bDst1 = (char*)Bs + (tid + 256) * 16;

    // fragment read byte-offsets (A: row=lane&15 of sub-tile, k=(lane>>4)*8)
    int aoff[4], boff[4];
#pragma unroll
    for (int m = 0; m < 4; ++m)
        aoff[m] = ((wm * 64 + m * 16 + (lane & 15)) * 32 + (lane >> 4) * 8) * 2;
#pragma unroll
    for (int n = 0; n < 4; ++n)
        boff[n] = ((wn * 64 + n * 16 + (lane & 15)) * 32 + (lane >> 4) * 8) * 2;

    for (int kt = 0; kt < K; kt += 32) {
        gload16(aSrc, aDst0);
        gload16(aSrc + rstride64, aDst1);
        gload16(bSrc, bDst0);
        gload16(bSrc + rstride64, bDst1);
        aSrc += 32;
        bSrc += 32;
        __syncthreads();   // compiler emits vmcnt(0) drain before barrier
        short8 af[4], bfr[4];
#pragma unroll
        for (int m = 0; m < 4; ++m)
            af[m] = *reinterpret_cast<const short8*>((const char*)As + aoff[m]);
#pragma unroll
        for (int n = 0; n < 4; ++n)
            bfr[n] = *reinterpret_cast<const short8*>((const char*)Bs + boff[n]);
#pragma unroll
        for (int m = 0; m < 4; ++m)
#pragma unroll
            for (int n = 0; n < 4; ++n)
                acc[m][n] = __builtin_amdgcn_mfma_f32_16x16x32_bf16(
                    af[m], bfr[n], acc[m][n], 0, 0, 0);
        __syncthreads();
    }

    float scale = sc[0];
    int crow = (lane >> 4) * 4;  // C/D: col=lane&15, row=(lane>>4)*4+reg (m89)
    int ccol = lane & 15;
#pragma unroll
    for (int m = 0; m < 4; ++m)
#pragma unroll
        for (int n = 0; n < 4; ++n)
#pragma unroll
            for (int r = 0; r < 4; ++r) {
                int grow = brow + wm * 64 + m * 16 + crow + r;
                int gcol = bcol + wn * 64 + n * 16 + ccol;
                C[(size_t)grow * N + gcol] = acc[m][n][r] * scale;
            }
}

// ---------------------------------------------------------------------------
// Fallback (only if ws too small for bf16 buffers): fused f32 tile GEMM with
// on-the-fly quantization. Slow but correct.
__global__ void gemm_fallback_k(const float* __restrict__ X,
                                const float* __restrict__ W,
                                float* __restrict__ C,
                                const float* __restrict__ sc,
                                int M, int N, int K) {
    __shared__ float Xs[32][33];
    __shared__ float Ws[32][33];
    float speps = sc[1];
    int nbn = N / 32;
    int brow = (blockIdx.x / nbn) * 32;
    int bcol = (blockIdx.x % nbn) * 32;
    int tx = threadIdx.x & 31;
    int ty4 = threadIdx.x >> 5;
    float acc[4] = {0.f, 0.f, 0.f, 0.f};
    for (int kt = 0; kt < K; kt += 32) {
#pragma unroll
        for (int i = 0; i < 4; ++i) {
            int idx = threadIdx.x + i * 256;
            int r = idx >> 5, c = idx & 31;
            Xs[r][c] = X[(size_t)(brow + r) * K + kt + c];
            float wv = W[(size_t)(bcol + r) * K + kt + c];
            float t = wv / speps;
            t = fminf(fmaxf(t, -1.f), 1.f);
            Ws[r][c] = rintf(t);
        }
        __syncthreads();
#pragma unroll
        for (int kk = 0; kk < 32; ++kk) {
            float wv = Ws[tx][kk];
#pragma unroll
            for (int i = 0; i < 4; ++i) acc[i] += Xs[ty4 * 4 + i][kk] * wv;
        }
        __syncthreads();
    }
    float scale = sc[0];
#pragma unroll
    for (int i = 0; i < 4; ++i)
        C[(size_t)(brow + ty4 * 4 + i) * N + (bcol + tx)] = acc[i] * scale;
}

// ---------------------------------------------------------------------------
extern "C" void kernel_launch(void* const* d_in, const int* in_sizes, int n_in,
                              void* d_out, int out_size, void* d_ws,
                              size_t ws_size, hipStream_t stream) {
    const float* x = (const float*)d_in[0];   // [B,S,K] f32
    const float* w = (const float*)d_in[1];   // [N,K]   f32
    float* out = (float*)d_out;               // [B,S,N] f32

    const int K = 4096;
    const int N = 4096;
    int xn = in_sizes[0];                     // M*K
    int wn = in_sizes[1];                     // N*K
    int M = xn / K;

    const int NPART = 2048;
    size_t off_sc = (size_t)NPART * 8;        // partials: 16 KiB
    size_t off_xb = off_sc + 64;              // 16-byte aligned
    size_t need = off_xb + ((size_t)xn + (size_t)wn) * 2;

    if (ws_size >= need) {
        double* partials = (double*)d_ws;
        float* sc = (float*)((char*)d_ws + off_sc);
        __hip_bfloat16* xb = (__hip_bfloat16*)((char*)d_ws + off_xb);
        __hip_bfloat16* wq = xb + xn;

        absmean_partial_k<<<NPART, 256, 0, stream>>>(w, partials);
        absmean_final_k<<<1, 256, 0, stream>>>(partials, sc, NPART, wn);
        quantize_w_k<<<wn / 2048, 256, 0, stream>>>(w, wq, sc);
        cast_x_k<<<xn / 2048, 256, 0, stream>>>(x, xb);
        dim3 grid((M / 128) * (N / 128));
        gemm_bt_k<<<grid, 256, 0, stream>>>(xb, wq, out, sc, M, N, K);
    } else {
        // minimal-scratch fallback: partials live in d_out (overwritten later)
        double* partials = (double*)d_out;
        float* sc = (float*)d_ws;  // needs only 8 bytes
        absmean_partial_k<<<NPART, 256, 0, stream>>>(w, partials);
        absmean_final_k<<<1, 256, 0, stream>>>(partials, sc, NPART, wn);
        dim3 grid((M / 32) * (N / 32));
        gemm_fallback_k<<<grid, 256, 0, stream>>>(x, w, out, sc, M, N, K);
    }
}

// Round 3
// 176.391 us; speedup vs baseline: 1.4449x; 1.4449x over previous
//
#include <hip/hip_runtime.h>
#include <hip/hip_bf16.h>
#include <stdint.h>
#include <stddef.h>

typedef __attribute__((ext_vector_type(8))) short short8;
typedef __attribute__((ext_vector_type(4))) float f32x4;
typedef __attribute__((ext_vector_type(8))) unsigned short ushort8;

// global -> LDS direct copy, 16B per lane. LDS dest must be base + lane*16.
__device__ __forceinline__ void gload16(const void* g, void* l) {
    __builtin_amdgcn_global_load_lds(
        (__attribute__((address_space(1))) void*)g,
        (__attribute__((address_space(3))) void*)l,
        16, 0, 0);
}

// ---------------------------------------------------------------------------
__global__ void absmean_partial_k(const float* __restrict__ w,
                                  double* __restrict__ partials) {
    int tid = threadIdx.x;
    size_t base = (size_t)blockIdx.x * 8192 + (size_t)tid * 4;
    float s = 0.f;
#pragma unroll
    for (int i = 0; i < 8; ++i) {
        f32x4 v = *reinterpret_cast<const f32x4*>(w + base + (size_t)i * 1024);
        s += __builtin_fabsf(v.x) + __builtin_fabsf(v.y) +
             __builtin_fabsf(v.z) + __builtin_fabsf(v.w);
    }
    double d = (double)s;
#pragma unroll
    for (int off = 32; off > 0; off >>= 1) d += __shfl_down(d, off, 64);
    __shared__ double red[4];
    int lane = tid & 63, wid = tid >> 6;
    if (lane == 0) red[wid] = d;
    __syncthreads();
    if (tid == 0) partials[blockIdx.x] = red[0] + red[1] + red[2] + red[3];
}

__global__ void absmean_final_k(const double* __restrict__ partials,
                                float* __restrict__ sc, int nparts, int count) {
    int tid = threadIdx.x;
    double d = 0.0;
    for (int i = tid; i < nparts; i += 256) d += partials[i];
#pragma unroll
    for (int off = 32; off > 0; off >>= 1) d += __shfl_down(d, off, 64);
    __shared__ double red[4];
    int lane = tid & 63, wid = tid >> 6;
    if (lane == 0) red[wid] = d;
    __syncthreads();
    if (tid == 0) {
        double total = red[0] + red[1] + red[2] + red[3];
        float scale = (float)(total / (double)count);
        sc[0] = scale;
        sc[1] = scale + 1e-8f;
    }
}

__global__ void quantize_w_k(const float* __restrict__ w,
                             __hip_bfloat16* __restrict__ wq,
                             const float* __restrict__ sc) {
    float speps = sc[1];
    size_t i = ((size_t)blockIdx.x * 256 + threadIdx.x) * 8;
    f32x4 a = *reinterpret_cast<const f32x4*>(w + i);
    f32x4 b = *reinterpret_cast<const f32x4*>(w + i + 4);
    float v[8] = {a.x, a.y, a.z, a.w, b.x, b.y, b.z, b.w};
    ushort8 o;
#pragma unroll
    for (int j = 0; j < 8; ++j) {
        float t = v[j] / speps;
        t = fminf(fmaxf(t, -1.f), 1.f);
        float r = rintf(t);
        __hip_bfloat16 h = __float2bfloat16(r);
        o[j] = *reinterpret_cast<unsigned short*>(&h);
    }
    *reinterpret_cast<ushort8*>(wq + i) = o;
}

__global__ void cast_x_k(const float* __restrict__ x,
                         __hip_bfloat16* __restrict__ xb) {
    size_t i = ((size_t)blockIdx.x * 256 + threadIdx.x) * 8;
    f32x4 a = *reinterpret_cast<const f32x4*>(x + i);
    f32x4 b = *reinterpret_cast<const f32x4*>(x + i + 4);
    float v[8] = {a.x, a.y, a.z, a.w, b.x, b.y, b.z, b.w};
    ushort8 o;
#pragma unroll
    for (int j = 0; j < 8; ++j) {
        __hip_bfloat16 h = __float2bfloat16(v[j]);
        o[j] = *reinterpret_cast<unsigned short*>(&h);
    }
    *reinterpret_cast<ushort8*>(xb + i) = o;
}

// ---------------------------------------------------------------------------
// 256x256 8-phase GEMM, quadrant decomposition (m201 template, corrected):
// each phase computes ONE block-wide C-quadrant (one A-half x one B-half)
// with all 8 waves, quad order (0,1),(1,1),(1,0),(0,0). Staging slots are
// region-retirement-ordered; counted vmcnt(6) at END of phases 1,2,4,5,6,8
// (before the closing barrier) so vmcnt->barrier->read holds across waves.
#define BUF1 65536

__global__ __launch_bounds__(512, 2) void gemm8_k(
    const __hip_bfloat16* __restrict__ A,   // [M][K]
    const __hip_bfloat16* __restrict__ B,   // [N][K]
    float* __restrict__ C,                  // [M][N]
    const float* __restrict__ sc, int M, int N, int K) {
    extern __shared__ char smem[];

    int nwg = gridDim.x, wg = blockIdx.x, swz = wg;
    if ((nwg & 7) == 0) { int cpx = nwg >> 3; swz = (wg & 7) * cpx + (wg >> 3); }
    int nbn = N >> 8;
    int brow = (swz / nbn) << 8, bcol = (swz % nbn) << 8;

    int tid = threadIdx.x, lane = tid & 63, wave = tid >> 6;
    int wm2 = wave >> 2, wn4 = wave & 3;          // 2x4 wave grid in quadrant
    int l15 = lane & 15, l16 = lane >> 4;
    int fl = ((l15 >> 2) & 1) << 5;               // st_16x32: bit5 ^= row bit2

    // region layout per buffer: A = [256 rows][128B] @0, B same @32768
    int aoffq0 = (((wm2 * 64 + l15) * 128) + l16 * 16) ^ fl;
    int aoffq1 = aoffq0 + 16384;                  // A-half1 (+128 rows)
    int boffq0 = 32768 + ((((wn4 * 32 + l15) * 128) + l16 * 16) ^ fl);
    int boffq1 = boffq0 + 16384;                  // B-half1

    // staging: dest byte d = tid*16 (linear); source logical = d ^ bit5(row2)
    int base_e = (tid * 16) ^ (tid & 32);
    int r0 = base_e >> 7;                         // 0..63
    int c0 = (base_e & 127) >> 1;                 // element col 0..63
    const __hip_bfloat16* sA = A + (size_t)(brow + r0) * K + c0;
    const __hip_bfloat16* sB = B + (size_t)(bcol + r0) * K + c0;
    size_t r64 = (size_t)64 * K, r128 = (size_t)128 * K;
    char* dA = smem + tid * 16;
    char* dB = smem + 32768 + tid * 16;

#define STG_A(BUF, H, KT) do { \
    const __hip_bfloat16* _s = sA + (size_t)(H) * r128 + (KT); \
    char* _d = dA + (BUF) + (H) * 16384; \
    gload16(_s, _d); gload16(_s + r64, _d + 8192); } while (0)
#define STG_B(BUF, H, KT) do { \
    const __hip_bfloat16* _s = sB + (size_t)(H) * r128 + (KT); \
    char* _d = dB + (BUF) + (H) * 16384; \
    gload16(_s, _d); gload16(_s + r64, _d + 8192); } while (0)

    f32x4 acc[4][8];
#pragma unroll
    for (int q = 0; q < 4; ++q)
#pragma unroll
        for (int f = 0; f < 8; ++f) acc[q][f] = (f32x4)(0.f);

    short8 aq[4][2], bq[2][2];

#define LDQ_A(BUF, AOFF) do { \
    _Pragma("unroll") for (int m2 = 0; m2 < 4; ++m2) { \
        aq[m2][0] = *(const short8*)(smem + (BUF) + (AOFF) + m2 * 2048); \
        aq[m2][1] = *(const short8*)(smem + (BUF) + (AOFF) + m2 * 2048 + 64); } } while (0)
#define LDQ_B(BUF, BOFF) do { \
    _Pragma("unroll") for (int n2 = 0; n2 < 2; ++n2) { \
        bq[n2][0] = *(const short8*)(smem + (BUF) + (BOFF) + n2 * 2048); \
        bq[n2][1] = *(const short8*)(smem + (BUF) + (BOFF) + n2 * 2048 + 64); } } while (0)
#define MM(Q) do { \
    __builtin_amdgcn_s_setprio(1); \
    _Pragma("unroll") for (int m2 = 0; m2 < 4; ++m2) \
    _Pragma("unroll") for (int n2 = 0; n2 < 2; ++n2) { \
        acc[Q][m2*2+n2] = __builtin_amdgcn_mfma_f32_16x16x32_bf16( \
            aq[m2][0], bq[n2][0], acc[Q][m2*2+n2], 0, 0, 0); \
        acc[Q][m2*2+n2] = __builtin_amdgcn_mfma_f32_16x16x32_bf16( \
            aq[m2][1], bq[n2][1], acc[Q][m2*2+n2], 0, 0, 0); } \
    __builtin_amdgcn_s_setprio(0); } while (0)
#define BAR __builtin_amdgcn_s_barrier()
#define LGKM asm volatile("s_waitcnt lgkmcnt(0)" ::: "memory")
#define VM6 asm volatile("s_waitcnt vmcnt(6)" ::: "memory")
#define VM4 asm volatile("s_waitcnt vmcnt(4)" ::: "memory")
#define VM2 asm volatile("s_waitcnt vmcnt(2)" ::: "memory")
#define VM0 asm volatile("s_waitcnt vmcnt(0)" ::: "memory")

    // prologue (slot order = steady-state p4..p8 of a virtual prior iter):
    // b0.B1(t0), b0.A0(t0), b0.A1(t0), b0.B0(t0), b1.B1(t1)
    STG_B(0, 1, 0); STG_A(0, 0, 0); STG_A(0, 1, 0); STG_B(0, 0, 0);
    STG_B(BUF1, 1, 64);
    VM6; BAR;   // first 2 halves (B1,A0 of tile0) guaranteed landed

    int nit = K / 128 - 1;  // full iterations; last one peeled
    for (int it = 0; it < nit; ++it) {
        int ktb1 = it * 128 + 64;    // tile 2it+1 -> buf1
        int ktb0n = it * 128 + 128;  // tile 2it+2 -> buf0
        int ktb1n = it * 128 + 192;  // tile 2it+3 -> buf1
        // p1: quad(0,1) of b0
        LDQ_A(0, aoffq0); LDQ_B(0, boffq1); STG_A(BUF1, 0, ktb1);
        BAR; LGKM; MM(1); VM6; BAR;
        // p2: quad(1,1)
        LDQ_A(0, aoffq1); STG_A(BUF1, 1, ktb1);
        BAR; LGKM; MM(3); VM6; BAR;
        // p3: quad(1,0)
        LDQ_B(0, boffq0); STG_B(BUF1, 0, ktb1);
        BAR; LGKM; MM(2); BAR;
        // p4: quad(0,0)   (A0 re-read; landed since p1)
        LDQ_A(0, aoffq0); STG_B(0, 1, ktb0n);
        BAR; LGKM; MM(0); VM6; BAR;
        // p5: quad(0,1) of b1
        LDQ_A(BUF1, aoffq0); LDQ_B(BUF1, boffq1); STG_A(0, 0, ktb0n);
        BAR; LGKM; MM(1); VM6; BAR;
        // p6: quad(1,1)
        LDQ_A(BUF1, aoffq1); STG_A(0, 1, ktb0n);
        BAR; LGKM; MM(3); VM6; BAR;
        // p7: quad(1,0)
        LDQ_B(BUF1, boffq0); STG_B(0, 0, ktb0n);
        BAR; LGKM; MM(2); BAR;
        // p8: quad(0,0)
        LDQ_A(BUF1, aoffq0); STG_B(BUF1, 1, ktb1n);
        BAR; LGKM; MM(0); VM6; BAR;
    }
    // peeled last iteration (tiles 2*nit, 2*nit+1): stage only tile 2*nit+1
    {
        int ktb1 = nit * 128 + 64;
        LDQ_A(0, aoffq0); LDQ_B(0, boffq1); STG_A(BUF1, 0, ktb1);
        BAR; LGKM; MM(1); VM6; BAR;
        LDQ_A(0, aoffq1); STG_A(BUF1, 1, ktb1);
        BAR; LGKM; MM(3); VM6; BAR;
        LDQ_B(0, boffq0); STG_B(BUF1, 0, ktb1);
        BAR; LGKM; MM(2); BAR;
        LDQ_A(0, aoffq0);
        BAR; LGKM; MM(0); VM4; BAR;
        LDQ_A(BUF1, aoffq0); LDQ_B(BUF1, boffq1);
        BAR; LGKM; MM(1); VM2; BAR;
        LDQ_A(BUF1, aoffq1);
        BAR; LGKM; MM(3); VM0; BAR;
        LDQ_B(BUF1, boffq0);
        BAR; LGKM; MM(2); BAR;
        LDQ_A(BUF1, aoffq0);
        BAR; LGKM; MM(0);
    }

    float scale = sc[0];
#pragma unroll
    for (int qm = 0; qm < 2; ++qm)
#pragma unroll
        for (int qn = 0; qn < 2; ++qn)
#pragma unroll
            for (int m2 = 0; m2 < 4; ++m2)
#pragma unroll
                for (int n2 = 0; n2 < 2; ++n2)
#pragma unroll
                    for (int r = 0; r < 4; ++r) {
                        int grow = brow + qm * 128 + wm2 * 64 + m2 * 16 + l16 * 4 + r;
                        int gcol = bcol + qn * 128 + wn4 * 32 + n2 * 16 + l15;
                        C[(size_t)grow * N + gcol] =
                            acc[qm * 2 + qn][m2 * 2 + n2][r] * scale;
                    }
}

// ---------------------------------------------------------------------------
__global__ void gemm_fallback_k(const float* __restrict__ X,
                                const float* __restrict__ W,
                                float* __restrict__ C,
                                const float* __restrict__ sc,
                                int M, int N, int K) {
    __shared__ float Xs[32][33];
    __shared__ float Ws[32][33];
    float speps = sc[1];
    int nbn = N / 32;
    int brow = (blockIdx.x / nbn) * 32;
    int bcol = (blockIdx.x % nbn) * 32;
    int tx = threadIdx.x & 31;
    int ty4 = threadIdx.x >> 5;
    float acc[4] = {0.f, 0.f, 0.f, 0.f};
    for (int kt = 0; kt < K; kt += 32) {
#pragma unroll
        for (int i = 0; i < 4; ++i) {
            int idx = threadIdx.x + i * 256;
            int r = idx >> 5, c = idx & 31;
            Xs[r][c] = X[(size_t)(brow + r) * K + kt + c];
            float wv = W[(size_t)(bcol + r) * K + kt + c];
            float t = wv / speps;
            t = fminf(fmaxf(t, -1.f), 1.f);
            Ws[r][c] = rintf(t);
        }
        __syncthreads();
#pragma unroll
        for (int kk = 0; kk < 32; ++kk) {
            float wv = Ws[tx][kk];
#pragma unroll
            for (int i = 0; i < 4; ++i) acc[i] += Xs[ty4 * 4 + i][kk] * wv;
        }
        __syncthreads();
    }
    float scale = sc[0];
#pragma unroll
    for (int i = 0; i < 4; ++i)
        C[(size_t)(brow + ty4 * 4 + i) * N + (bcol + tx)] = acc[i] * scale;
}

// ---------------------------------------------------------------------------
extern "C" void kernel_launch(void* const* d_in, const int* in_sizes, int n_in,
                              void* d_out, int out_size, void* d_ws,
                              size_t ws_size, hipStream_t stream) {
    const float* x = (const float*)d_in[0];   // [B,S,K] f32
    const float* w = (const float*)d_in[1];   // [N,K]   f32
    float* out = (float*)d_out;               // [B,S,N] f32

    const int K = 4096;
    const int N = 4096;
    int xn = in_sizes[0];                     // M*K
    int wn = in_sizes[1];                     // N*K
    int M = xn / K;

    const int NPART = 2048;
    size_t off_sc = (size_t)NPART * 8;
    size_t off_xb = off_sc + 64;
    size_t need = off_xb + ((size_t)xn + (size_t)wn) * 2;

    bool shape_ok = (M % 256 == 0) && (N % 256 == 0) && (K % 128 == 0);

    if (ws_size >= need && shape_ok) {
        double* partials = (double*)d_ws;
        float* sc = (float*)((char*)d_ws + off_sc);
        __hip_bfloat16* xb = (__hip_bfloat16*)((char*)d_ws + off_xb);
        __hip_bfloat16* wq = xb + xn;

        absmean_partial_k<<<NPART, 256, 0, stream>>>(w, partials);
        absmean_final_k<<<1, 256, 0, stream>>>(partials, sc, NPART, wn);
        quantize_w_k<<<wn / 2048, 256, 0, stream>>>(w, wq, sc);
        cast_x_k<<<xn / 2048, 256, 0, stream>>>(x, xb);

        hipFuncSetAttribute(reinterpret_cast<const void*>(gemm8_k),
                            hipFuncAttributeMaxDynamicSharedMemorySize, 131072);
        dim3 grid((M / 256) * (N / 256));
        gemm8_k<<<grid, 512, 131072, stream>>>(xb, wq, out, sc, M, N, K);
    } else {
        double* partials = (double*)d_out;
        float* sc = (float*)d_ws;
        absmean_partial_k<<<NPART, 256, 0, stream>>>(w, partials);
        absmean_final_k<<<1, 256, 0, stream>>>(partials, sc, NPART, wn);
        dim3 grid((M / 32) * (N / 32));
        gemm_fallback_k<<<grid, 256, 0, stream>>>(x, w, out, sc, M, N, K);
    }
}

// Round 4
// 164.391 us; speedup vs baseline: 1.5504x; 1.0730x over previous
//
#include <hip/hip_runtime.h>
#include <hip/hip_bf16.h>
#include <stdint.h>
#include <stddef.h>

typedef __attribute__((ext_vector_type(8))) short short8;
typedef __attribute__((ext_vector_type(4))) float f32x4;
typedef __attribute__((ext_vector_type(8))) unsigned short ushort8;

// global -> LDS direct copy, 16B per lane. LDS dest must be base + lane*16.
__device__ __forceinline__ void gload16(const void* g, void* l) {
    __builtin_amdgcn_global_load_lds(
        (__attribute__((address_space(1))) void*)g,
        (__attribute__((address_space(3))) void*)l,
        16, 0, 0);
}

// ---------------------------------------------------------------------------
__global__ void absmean_partial_k(const float* __restrict__ w,
                                  double* __restrict__ partials) {
    int tid = threadIdx.x;
    size_t base = (size_t)blockIdx.x * 8192 + (size_t)tid * 4;
    float s = 0.f;
#pragma unroll
    for (int i = 0; i < 8; ++i) {
        f32x4 v = *reinterpret_cast<const f32x4*>(w + base + (size_t)i * 1024);
        s += __builtin_fabsf(v.x) + __builtin_fabsf(v.y) +
             __builtin_fabsf(v.z) + __builtin_fabsf(v.w);
    }
    double d = (double)s;
#pragma unroll
    for (int off = 32; off > 0; off >>= 1) d += __shfl_down(d, off, 64);
    __shared__ double red[4];
    int lane = tid & 63, wid = tid >> 6;
    if (lane == 0) red[wid] = d;
    __syncthreads();
    if (tid == 0) partials[blockIdx.x] = red[0] + red[1] + red[2] + red[3];
}

__global__ void absmean_final_k(const double* __restrict__ partials,
                                float* __restrict__ sc, int nparts, int count) {
    int tid = threadIdx.x;
    double d = 0.0;
    for (int i = tid; i < nparts; i += 256) d += partials[i];
#pragma unroll
    for (int off = 32; off > 0; off >>= 1) d += __shfl_down(d, off, 64);
    __shared__ double red[4];
    int lane = tid & 63, wid = tid >> 6;
    if (lane == 0) red[wid] = d;
    __syncthreads();
    if (tid == 0) {
        double total = red[0] + red[1] + red[2] + red[3];
        float scale = (float)(total / (double)count);
        sc[0] = scale;
        sc[1] = scale + 1e-8f;
    }
}

__global__ void quantize_w_k(const float* __restrict__ w,
                             __hip_bfloat16* __restrict__ wq,
                             const float* __restrict__ sc) {
    float speps = sc[1];
    size_t i = ((size_t)blockIdx.x * 256 + threadIdx.x) * 8;
    f32x4 a = *reinterpret_cast<const f32x4*>(w + i);
    f32x4 b = *reinterpret_cast<const f32x4*>(w + i + 4);
    float v[8] = {a.x, a.y, a.z, a.w, b.x, b.y, b.z, b.w};
    ushort8 o;
#pragma unroll
    for (int j = 0; j < 8; ++j) {
        float t = v[j] / speps;
        t = fminf(fmaxf(t, -1.f), 1.f);
        float r = rintf(t);
        __hip_bfloat16 h = __float2bfloat16(r);
        o[j] = *reinterpret_cast<unsigned short*>(&h);
    }
    *reinterpret_cast<ushort8*>(wq + i) = o;
}

__global__ void cast_x_k(const float* __restrict__ x,
                         __hip_bfloat16* __restrict__ xb) {
    size_t i = ((size_t)blockIdx.x * 256 + threadIdx.x) * 8;
    f32x4 a = *reinterpret_cast<const f32x4*>(x + i);
    f32x4 b = *reinterpret_cast<const f32x4*>(x + i + 4);
    float v[8] = {a.x, a.y, a.z, a.w, b.x, b.y, b.z, b.w};
    ushort8 o;
#pragma unroll
    for (int j = 0; j < 8; ++j) {
        __hip_bfloat16 h = __float2bfloat16(v[j]);
        o[j] = *reinterpret_cast<unsigned short*>(&h);
    }
    *reinterpret_cast<ushort8*>(xb + i) = o;
}

// ---------------------------------------------------------------------------
// 256x256 8-phase GEMM, quadrant decomposition. Schedule identical to the
// round-3 passing kernel; ONLY the LDS swizzle changed: full 3-bit XOR
// (byte ^= ((row&7)<<4)) on both the pre-swizzled global staging source and
// the fragment ds_reads (rule #21: both-sides-or-neither). The second K-half
// fragment read is off^64 (swizzle occupies bit 6 -> XOR, not add).
#define BUF1 65536

__global__ __launch_bounds__(512, 2) void gemm8_k(
    const __hip_bfloat16* __restrict__ A,   // [M][K]
    const __hip_bfloat16* __restrict__ B,   // [N][K]
    float* __restrict__ C,                  // [M][N]
    const float* __restrict__ sc, int M, int N, int K) {
    extern __shared__ char smem[];

    int nwg = gridDim.x, wg = blockIdx.x, swz = wg;
    if ((nwg & 7) == 0) { int cpx = nwg >> 3; swz = (wg & 7) * cpx + (wg >> 3); }
    int nbn = N >> 8;
    int brow = (swz / nbn) << 8, bcol = (swz % nbn) << 8;

    int tid = threadIdx.x, lane = tid & 63, wave = tid >> 6;
    int wm2 = wave >> 2, wn4 = wave & 3;          // 2x4 wave grid in quadrant
    int l15 = lane & 15, l16 = lane >> 4;
    int swl = (l15 & 7) << 4;                     // 3-bit row-XOR swizzle

    // region layout per buffer: A = [256 rows][128B] @0, B same @32768.
    // (row&7) is invariant under +64/+128-row region offsets, so one XOR
    // term serves q0/q1 and both staging halves.
    int aoffq0 = (wm2 * 64 + l15) * 128 + ((l16 * 16) ^ swl);
    int aoffq1 = aoffq0 + 16384;                  // A-half1 (+128 rows)
    int boffq0 = 32768 + (wn4 * 32 + l15) * 128 + ((l16 * 16) ^ swl);
    int boffq1 = boffq0 + 16384;                  // B-half1

    // staging: dest byte d = tid*16 (linear); source logical = d ^ ((row&7)<<4)
    int sw_t = ((tid >> 3) & 7) << 4;
    int base_e = (tid * 16) ^ sw_t;
    int r0 = base_e >> 7;                         // 0..63
    int c0 = (base_e & 127) >> 1;                 // element col 0..63
    const __hip_bfloat16* sA = A + (size_t)(brow + r0) * K + c0;
    const __hip_bfloat16* sB = B + (size_t)(bcol + r0) * K + c0;
    size_t r64 = (size_t)64 * K, r128 = (size_t)128 * K;
    char* dA = smem + tid * 16;
    char* dB = smem + 32768 + tid * 16;

#define STG_A(BUF, H, KT) do { \
    const __hip_bfloat16* _s = sA + (size_t)(H) * r128 + (KT); \
    char* _d = dA + (BUF) + (H) * 16384; \
    gload16(_s, _d); gload16(_s + r64, _d + 8192); } while (0)
#define STG_B(BUF, H, KT) do { \
    const __hip_bfloat16* _s = sB + (size_t)(H) * r128 + (KT); \
    char* _d = dB + (BUF) + (H) * 16384; \
    gload16(_s, _d); gload16(_s + r64, _d + 8192); } while (0)

    f32x4 acc[4][8];
#pragma unroll
    for (int q = 0; q < 4; ++q)
#pragma unroll
        for (int f = 0; f < 8; ++f) acc[q][f] = (f32x4)(0.f);

    short8 aq[4][2], bq[2][2];

#define LDQ_A(BUF, AOFF) do { \
    _Pragma("unroll") for (int m2 = 0; m2 < 4; ++m2) { \
        aq[m2][0] = *(const short8*)(smem + (BUF) + (AOFF) + m2 * 2048); \
        aq[m2][1] = *(const short8*)(smem + (BUF) + ((AOFF) ^ 64) + m2 * 2048); } } while (0)
#define LDQ_B(BUF, BOFF) do { \
    _Pragma("unroll") for (int n2 = 0; n2 < 2; ++n2) { \
        bq[n2][0] = *(const short8*)(smem + (BUF) + (BOFF) + n2 * 2048); \
        bq[n2][1] = *(const short8*)(smem + (BUF) + ((BOFF) ^ 64) + n2 * 2048); } } while (0)
#define MM(Q) do { \
    __builtin_amdgcn_s_setprio(1); \
    _Pragma("unroll") for (int m2 = 0; m2 < 4; ++m2) \
    _Pragma("unroll") for (int n2 = 0; n2 < 2; ++n2) { \
        acc[Q][m2*2+n2] = __builtin_amdgcn_mfma_f32_16x16x32_bf16( \
            aq[m2][0], bq[n2][0], acc[Q][m2*2+n2], 0, 0, 0); \
        acc[Q][m2*2+n2] = __builtin_amdgcn_mfma_f32_16x16x32_bf16( \
            aq[m2][1], bq[n2][1], acc[Q][m2*2+n2], 0, 0, 0); } \
    __builtin_amdgcn_s_setprio(0); } while (0)
#define BAR __builtin_amdgcn_s_barrier()
#define LGKM asm volatile("s_waitcnt lgkmcnt(0)" ::: "memory")
#define VM6 asm volatile("s_waitcnt vmcnt(6)" ::: "memory")
#define VM4 asm volatile("s_waitcnt vmcnt(4)" ::: "memory")
#define VM2 asm volatile("s_waitcnt vmcnt(2)" ::: "memory")
#define VM0 asm volatile("s_waitcnt vmcnt(0)" ::: "memory")

    // prologue: b0.B1(t0), b0.A0(t0), b0.A1(t0), b0.B0(t0), b1.B1(t1)
    STG_B(0, 1, 0); STG_A(0, 0, 0); STG_A(0, 1, 0); STG_B(0, 0, 0);
    STG_B(BUF1, 1, 64);
    VM6; BAR;   // B1,A0 of tile0 guaranteed landed

    int nit = K / 128 - 1;  // full iterations; last one peeled
    for (int it = 0; it < nit; ++it) {
        int ktb1 = it * 128 + 64;    // tile 2it+1 -> buf1
        int ktb0n = it * 128 + 128;  // tile 2it+2 -> buf0
        int ktb1n = it * 128 + 192;  // tile 2it+3 -> buf1
        // p1: quad(0,1) of b0
        LDQ_A(0, aoffq0); LDQ_B(0, boffq1); STG_A(BUF1, 0, ktb1);
        BAR; LGKM; MM(1); VM6; BAR;
        // p2: quad(1,1)
        LDQ_A(0, aoffq1); STG_A(BUF1, 1, ktb1);
        BAR; LGKM; MM(3); VM6; BAR;
        // p3: quad(1,0)
        LDQ_B(0, boffq0); STG_B(BUF1, 0, ktb1);
        BAR; LGKM; MM(2); BAR;
        // p4: quad(0,0)
        LDQ_A(0, aoffq0); STG_B(0, 1, ktb0n);
        BAR; LGKM; MM(0); VM6; BAR;
        // p5: quad(0,1) of b1
        LDQ_A(BUF1, aoffq0); LDQ_B(BUF1, boffq1); STG_A(0, 0, ktb0n);
        BAR; LGKM; MM(1); VM6; BAR;
        // p6: quad(1,1)
        LDQ_A(BUF1, aoffq1); STG_A(0, 1, ktb0n);
        BAR; LGKM; MM(3); VM6; BAR;
        // p7: quad(1,0)
        LDQ_B(BUF1, boffq0); STG_B(0, 0, ktb0n);
        BAR; LGKM; MM(2); BAR;
        // p8: quad(0,0)
        LDQ_A(BUF1, aoffq0); STG_B(BUF1, 1, ktb1n);
        BAR; LGKM; MM(0); VM6; BAR;
    }
    // peeled last iteration (tiles 2*nit, 2*nit+1): stage only tile 2*nit+1
    {
        int ktb1 = nit * 128 + 64;
        LDQ_A(0, aoffq0); LDQ_B(0, boffq1); STG_A(BUF1, 0, ktb1);
        BAR; LGKM; MM(1); VM6; BAR;
        LDQ_A(0, aoffq1); STG_A(BUF1, 1, ktb1);
        BAR; LGKM; MM(3); VM6; BAR;
        LDQ_B(0, boffq0); STG_B(BUF1, 0, ktb1);
        BAR; LGKM; MM(2); BAR;
        LDQ_A(0, aoffq0);
        BAR; LGKM; MM(0); VM4; BAR;
        LDQ_A(BUF1, aoffq0); LDQ_B(BUF1, boffq1);
        BAR; LGKM; MM(1); VM2; BAR;
        LDQ_A(BUF1, aoffq1);
        BAR; LGKM; MM(3); VM0; BAR;
        LDQ_B(BUF1, boffq0);
        BAR; LGKM; MM(2); BAR;
        LDQ_A(BUF1, aoffq0);
        BAR; LGKM; MM(0);
    }

    float scale = sc[0];
#pragma unroll
    for (int qm = 0; qm < 2; ++qm)
#pragma unroll
        for (int qn = 0; qn < 2; ++qn)
#pragma unroll
            for (int m2 = 0; m2 < 4; ++m2)
#pragma unroll
                for (int n2 = 0; n2 < 2; ++n2)
#pragma unroll
                    for (int r = 0; r < 4; ++r) {
                        int grow = brow + qm * 128 + wm2 * 64 + m2 * 16 + l16 * 4 + r;
                        int gcol = bcol + qn * 128 + wn4 * 32 + n2 * 16 + l15;
                        C[(size_t)grow * N + gcol] =
                            acc[qm * 2 + qn][m2 * 2 + n2][r] * scale;
                    }
}

// ---------------------------------------------------------------------------
__global__ void gemm_fallback_k(const float* __restrict__ X,
                                const float* __restrict__ W,
                                float* __restrict__ C,
                                const float* __restrict__ sc,
                                int M, int N, int K) {
    __shared__ float Xs[32][33];
    __shared__ float Ws[32][33];
    float speps = sc[1];
    int nbn = N / 32;
    int brow = (blockIdx.x / nbn) * 32;
    int bcol = (blockIdx.x % nbn) * 32;
    int tx = threadIdx.x & 31;
    int ty4 = threadIdx.x >> 5;
    float acc[4] = {0.f, 0.f, 0.f, 0.f};
    for (int kt = 0; kt < K; kt += 32) {
#pragma unroll
        for (int i = 0; i < 4; ++i) {
            int idx = threadIdx.x + i * 256;
            int r = idx >> 5, c = idx & 31;
            Xs[r][c] = X[(size_t)(brow + r) * K + kt + c];
            float wv = W[(size_t)(bcol + r) * K + kt + c];
            float t = wv / speps;
            t = fminf(fmaxf(t, -1.f), 1.f);
            Ws[r][c] = rintf(t);
        }
        __syncthreads();
#pragma unroll
        for (int kk = 0; kk < 32; ++kk) {
            float wv = Ws[tx][kk];
#pragma unroll
            for (int i = 0; i < 4; ++i) acc[i] += Xs[ty4 * 4 + i][kk] * wv;
        }
        __syncthreads();
    }
    float scale = sc[0];
#pragma unroll
    for (int i = 0; i < 4; ++i)
        C[(size_t)(brow + ty4 * 4 + i) * N + (bcol + tx)] = acc[i] * scale;
}

// ---------------------------------------------------------------------------
extern "C" void kernel_launch(void* const* d_in, const int* in_sizes, int n_in,
                              void* d_out, int out_size, void* d_ws,
                              size_t ws_size, hipStream_t stream) {
    const float* x = (const float*)d_in[0];   // [B,S,K] f32
    const float* w = (const float*)d_in[1];   // [N,K]   f32
    float* out = (float*)d_out;               // [B,S,N] f32

    const int K = 4096;
    const int N = 4096;
    int xn = in_sizes[0];                     // M*K
    int wn = in_sizes[1];                     // N*K
    int M = xn / K;

    const int NPART = 2048;
    size_t off_sc = (size_t)NPART * 8;
    size_t off_xb = off_sc + 64;
    size_t need = off_xb + ((size_t)xn + (size_t)wn) * 2;

    bool shape_ok = (M % 256 == 0) && (N % 256 == 0) && (K % 128 == 0);

    if (ws_size >= need && shape_ok) {
        double* partials = (double*)d_ws;
        float* sc = (float*)((char*)d_ws + off_sc);
        __hip_bfloat16* xb = (__hip_bfloat16*)((char*)d_ws + off_xb);
        __hip_bfloat16* wq = xb + xn;

        absmean_partial_k<<<NPART, 256, 0, stream>>>(w, partials);
        absmean_final_k<<<1, 256, 0, stream>>>(partials, sc, NPART, wn);
        quantize_w_k<<<wn / 2048, 256, 0, stream>>>(w, wq, sc);
        cast_x_k<<<xn / 2048, 256, 0, stream>>>(x, xb);

        hipFuncSetAttribute(reinterpret_cast<const void*>(gemm8_k),
                            hipFuncAttributeMaxDynamicSharedMemorySize, 131072);
        dim3 grid((M / 256) * (N / 256));
        gemm8_k<<<grid, 512, 131072, stream>>>(xb, wq, out, sc, M, N, K);
    } else {
        double* partials = (double*)d_out;
        float* sc = (float*)d_ws;
        absmean_partial_k<<<NPART, 256, 0, stream>>>(w, partials);
        absmean_final_k<<<1, 256, 0, stream>>>(partials, sc, NPART, wn);
        dim3 grid((M / 32) * (N / 32));
        gemm_fallback_k<<<grid, 256, 0, stream>>>(x, w, out, sc, M, N, K);
    }
}

// Round 5
// 161.785 us; speedup vs baseline: 1.5754x; 1.0161x over previous
//
#include <hip/hip_runtime.h>
#include <hip/hip_bf16.h>
#include <stdint.h>
#include <stddef.h>

typedef __attribute__((ext_vector_type(8))) short short8;
typedef __attribute__((ext_vector_type(4))) float f32x4;
typedef __attribute__((ext_vector_type(8))) unsigned short ushort8;

// global -> LDS direct copy, 16B per lane. LDS dest must be base + lane*16.
__device__ __forceinline__ void gload16(const void* g, void* l) {
    __builtin_amdgcn_global_load_lds(
        (__attribute__((address_space(1))) void*)g,
        (__attribute__((address_space(3))) void*)l,
        16, 0, 0);
}

// ---------------------------------------------------------------------------
__global__ void absmean_partial_k(const float* __restrict__ w,
                                  double* __restrict__ partials) {
    int tid = threadIdx.x;
    size_t base = (size_t)blockIdx.x * 8192 + (size_t)tid * 4;
    float s = 0.f;
#pragma unroll
    for (int i = 0; i < 8; ++i) {
        f32x4 v = *reinterpret_cast<const f32x4*>(w + base + (size_t)i * 1024);
        s += __builtin_fabsf(v.x) + __builtin_fabsf(v.y) +
             __builtin_fabsf(v.z) + __builtin_fabsf(v.w);
    }
    double d = (double)s;
#pragma unroll
    for (int off = 32; off > 0; off >>= 1) d += __shfl_down(d, off, 64);
    __shared__ double red[4];
    int lane = tid & 63, wid = tid >> 6;
    if (lane == 0) red[wid] = d;
    __syncthreads();
    if (tid == 0) partials[blockIdx.x] = red[0] + red[1] + red[2] + red[3];
}

__global__ void absmean_final_k(const double* __restrict__ partials,
                                float* __restrict__ sc, int nparts, int count) {
    int tid = threadIdx.x;
    double d = 0.0;
    for (int i = tid; i < nparts; i += 256) d += partials[i];
#pragma unroll
    for (int off = 32; off > 0; off >>= 1) d += __shfl_down(d, off, 64);
    __shared__ double red[4];
    int lane = tid & 63, wid = tid >> 6;
    if (lane == 0) red[wid] = d;
    __syncthreads();
    if (tid == 0) {
        double total = red[0] + red[1] + red[2] + red[3];
        float scale = (float)(total / (double)count);
        sc[0] = scale;
        sc[1] = scale + 1e-8f;
    }
}

__global__ void quantize_w_k(const float* __restrict__ w,
                             __hip_bfloat16* __restrict__ wq,
                             const float* __restrict__ sc) {
    float speps = sc[1];
    size_t i = ((size_t)blockIdx.x * 256 + threadIdx.x) * 8;
    f32x4 a = *reinterpret_cast<const f32x4*>(w + i);
    f32x4 b = *reinterpret_cast<const f32x4*>(w + i + 4);
    float v[8] = {a.x, a.y, a.z, a.w, b.x, b.y, b.z, b.w};
    ushort8 o;
#pragma unroll
    for (int j = 0; j < 8; ++j) {
        float t = v[j] / speps;
        t = fminf(fmaxf(t, -1.f), 1.f);
        float r = rintf(t);
        __hip_bfloat16 h = __float2bfloat16(r);
        o[j] = *reinterpret_cast<unsigned short*>(&h);
    }
    *reinterpret_cast<ushort8*>(wq + i) = o;
}

__global__ void cast_x_k(const float* __restrict__ x,
                         __hip_bfloat16* __restrict__ xb) {
    size_t i = ((size_t)blockIdx.x * 256 + threadIdx.x) * 8;
    f32x4 a = *reinterpret_cast<const f32x4*>(x + i);
    f32x4 b = *reinterpret_cast<const f32x4*>(x + i + 4);
    float v[8] = {a.x, a.y, a.z, a.w, b.x, b.y, b.z, b.w};
    ushort8 o;
#pragma unroll
    for (int j = 0; j < 8; ++j) {
        __hip_bfloat16 h = __float2bfloat16(v[j]);
        o[j] = *reinterpret_cast<unsigned short*>(&h);
    }
    *reinterpret_cast<ushort8*>(xb + i) = o;
}

// ---------------------------------------------------------------------------
// 256x256 8-phase GEMM, wave-ownership tiling: wave (wm2,wn4) owns a 128x64
// output tile (rows wm2*128.., cols wn4*64..). Phases = quadrants of the
// wave tile with PERSISTENT operand registers: per K-tile only 24 ds_read_b128
// per wave (the floor): p1: A-mq0(8)+B-nq0(4), p2: B-nq1(4), p3: A-mq1(8),
// p4: none (reuses bq0 from p1). Staging slots re-derived for the new region
// lifetimes; VM6 only at ends of p2/p4/p6/p8. 3-bit row-XOR LDS swizzle
// (round-4, conflict-free) unchanged.
#define BUF1 65536

__global__ __launch_bounds__(512, 2) void gemm8_k(
    const __hip_bfloat16* __restrict__ A,   // [M][K]
    const __hip_bfloat16* __restrict__ B,   // [N][K]
    float* __restrict__ C,                  // [M][N]
    const float* __restrict__ sc, int M, int N, int K) {
    extern __shared__ char smem[];

    int nwg = gridDim.x, wg = blockIdx.x, swz = wg;
    if ((nwg & 7) == 0) { int cpx = nwg >> 3; swz = (wg & 7) * cpx + (wg >> 3); }
    int nbn = N >> 8;
    int brow = (swz / nbn) << 8, bcol = (swz % nbn) << 8;

    int tid = threadIdx.x, lane = tid & 63, wave = tid >> 6;
    int wm2 = wave >> 2, wn4 = wave & 3;          // 2x4 wave grid
    int l15 = lane & 15, l16 = lane >> 4;
    int swl = (l15 & 7) << 4;                     // 3-bit row-XOR swizzle

    // regions per buffer: A = [256 rows][128B] @0, B same @32768.
    // wave's A rows: wm2*128 + mq*64 + m2*16 + l15 ; B rows: wn4*64 + nq*32 + n2*16 + l15
    int aoffb = (wm2 * 128 + l15) * 128 + ((l16 * 16) ^ swl);
    int boffb = 32768 + (wn4 * 64 + l15) * 128 + ((l16 * 16) ^ swl);

    // staging: dest byte d = tid*16 (linear); source logical = d ^ ((row&7)<<4)
    int sw_t = ((tid >> 3) & 7) << 4;
    int base_e = (tid * 16) ^ sw_t;
    int r0 = base_e >> 7;                         // 0..63
    int c0 = (base_e & 127) >> 1;                 // element col 0..63
    const __hip_bfloat16* sA = A + (size_t)(brow + r0) * K + c0;
    const __hip_bfloat16* sB = B + (size_t)(bcol + r0) * K + c0;
    size_t r64 = (size_t)64 * K, r128 = (size_t)128 * K;
    char* dA = smem + tid * 16;
    char* dB = smem + 32768 + tid * 16;

#define STG_A(BUF, H, KT) do { \
    const __hip_bfloat16* _s = sA + (size_t)(H) * r128 + (KT); \
    char* _d = dA + (BUF) + (H) * 16384; \
    gload16(_s, _d); gload16(_s + r64, _d + 8192); } while (0)
#define STG_B(BUF, H, KT) do { \
    const __hip_bfloat16* _s = sB + (size_t)(H) * r128 + (KT); \
    char* _d = dB + (BUF) + (H) * 16384; \
    gload16(_s, _d); gload16(_s + r64, _d + 8192); } while (0)

    f32x4 acc[4][8];   // [mq*2+nq][m2*2+n2]
#pragma unroll
    for (int q = 0; q < 4; ++q)
#pragma unroll
        for (int f = 0; f < 8; ++f) acc[q][f] = (f32x4)(0.f);

    short8 aq[4][2];    // current A m-quad frags (4 m2 x 2 k-halves)
    short8 bq0[2][2];   // B nq0 frags -- persist p1..p4
    short8 bq1[2][2];   // B nq1 frags

#define LDQ_A(BUF, MQ) do { \
    _Pragma("unroll") for (int m2 = 0; m2 < 4; ++m2) { \
        int _o = aoffb + (MQ) * 8192 + m2 * 2048; \
        aq[m2][0] = *(const short8*)(smem + (BUF) + _o); \
        aq[m2][1] = *(const short8*)(smem + (BUF) + (_o ^ 64)); } } while (0)
#define LDQ_B(BUF, NQ, BQ) do { \
    _Pragma("unroll") for (int n2 = 0; n2 < 2; ++n2) { \
        int _o = boffb + (NQ) * 4096 + n2 * 2048; \
        BQ[n2][0] = *(const short8*)(smem + (BUF) + _o); \
        BQ[n2][1] = *(const short8*)(smem + (BUF) + (_o ^ 64)); } } while (0)
#define MM(Q, BQ) do { \
    __builtin_amdgcn_s_setprio(1); \
    _Pragma("unroll") for (int m2 = 0; m2 < 4; ++m2) \
    _Pragma("unroll") for (int n2 = 0; n2 < 2; ++n2) { \
        acc[Q][m2*2+n2] = __builtin_amdgcn_mfma_f32_16x16x32_bf16( \
            aq[m2][0], BQ[n2][0], acc[Q][m2*2+n2], 0, 0, 0); \
        acc[Q][m2*2+n2] = __builtin_amdgcn_mfma_f32_16x16x32_bf16( \
            aq[m2][1], BQ[n2][1], acc[Q][m2*2+n2], 0, 0, 0); } \
    __builtin_amdgcn_s_setprio(0); } while (0)
#define BAR __builtin_amdgcn_s_barrier()
#define LGKM asm volatile("s_waitcnt lgkmcnt(0)" ::: "memory")
#define VM6 asm volatile("s_waitcnt vmcnt(6)" ::: "memory")
#define VM4 asm volatile("s_waitcnt vmcnt(4)" ::: "memory")
#define VM2 asm volatile("s_waitcnt vmcnt(2)" ::: "memory")
#define VM0 asm volatile("s_waitcnt vmcnt(0)" ::: "memory")

    // prologue: tile0 -> b0 (A0,B0,B1,A1), tile1 B-halves -> b1.
    // VM4 completes the first 8 loads (all of b0); b1.B0/B1 stay in flight.
    STG_A(0, 0, 0); STG_B(0, 0, 0); STG_B(0, 1, 0); STG_A(0, 1, 0);
    STG_B(BUF1, 0, 64); STG_B(BUF1, 1, 64);
    VM4; BAR;

    int nit = K / 128 - 1;  // full iterations; last one peeled
    for (int it = 0; it < nit; ++it) {
        int ktb1 = it * 128 + 64;    // tile 2it+1 -> b1
        int ktn  = it * 128 + 128;   // tile 2it+2 -> b0
        int ktn1 = it * 128 + 192;   // tile 2it+3 -> b1
        // p1: wave-quad (mq0,nq0) of b0
        LDQ_A(0, 0); LDQ_B(0, 0, bq0); STG_A(BUF1, 0, ktb1);
        BAR; LGKM; MM(0, bq0); BAR;
        // p2: (mq0,nq1)
        LDQ_B(0, 1, bq1); STG_A(BUF1, 1, ktb1);
        BAR; LGKM; MM(1, bq1); VM6; BAR;
        // p3: (mq1,nq1)
        LDQ_A(0, 1); STG_B(0, 0, ktn);
        BAR; LGKM; MM(3, bq1); BAR;
        // p4: (mq1,nq0) -- no ds_reads (bq0 persisted)
        STG_B(0, 1, ktn);
        BAR; MM(2, bq0); VM6; BAR;
        // p5: (mq0,nq0) of b1
        LDQ_A(BUF1, 0); LDQ_B(BUF1, 0, bq0); STG_A(0, 0, ktn);
        BAR; LGKM; MM(0, bq0); BAR;
        // p6: (mq0,nq1)
        LDQ_B(BUF1, 1, bq1); STG_A(0, 1, ktn);
        BAR; LGKM; MM(1, bq1); VM6; BAR;
        // p7: (mq1,nq1)
        LDQ_A(BUF1, 1); STG_B(BUF1, 0, ktn1);
        BAR; LGKM; MM(3, bq1); BAR;
        // p8: (mq1,nq0)
        STG_B(BUF1, 1, ktn1);
        BAR; MM(2, bq0); VM6; BAR;
    }
    // peeled last iteration (tiles 2*nit, 2*nit+1): stage only b1.A0/A1
    {
        int ktb1 = nit * 128 + 64;
        LDQ_A(0, 0); LDQ_B(0, 0, bq0); STG_A(BUF1, 0, ktb1);
        BAR; LGKM; MM(0, bq0); BAR;
        LDQ_B(0, 1, bq1); STG_A(BUF1, 1, ktb1);
        BAR; LGKM; MM(1, bq1); VM6; BAR;
        LDQ_A(0, 1);
        BAR; LGKM; MM(3, bq1); BAR;
        BAR; MM(2, bq0); VM2; BAR;
        LDQ_A(BUF1, 0); LDQ_B(BUF1, 0, bq0);
        BAR; LGKM; MM(0, bq0); BAR;
        LDQ_B(BUF1, 1, bq1);
        BAR; LGKM; MM(1, bq1); VM0; BAR;
        LDQ_A(BUF1, 1);
        BAR; LGKM; MM(3, bq1); BAR;
        BAR; MM(2, bq0);
    }

    float scale = sc[0];
#pragma unroll
    for (int mq = 0; mq < 2; ++mq)
#pragma unroll
        for (int nq = 0; nq < 2; ++nq)
#pragma unroll
            for (int m2 = 0; m2 < 4; ++m2)
#pragma unroll
                for (int n2 = 0; n2 < 2; ++n2)
#pragma unroll
                    for (int r = 0; r < 4; ++r) {
                        int grow = brow + wm2 * 128 + mq * 64 + m2 * 16 + l16 * 4 + r;
                        int gcol = bcol + wn4 * 64 + nq * 32 + n2 * 16 + l15;
                        C[(size_t)grow * N + gcol] =
                            acc[mq * 2 + nq][m2 * 2 + n2][r] * scale;
                    }
}

// ---------------------------------------------------------------------------
__global__ void gemm_fallback_k(const float* __restrict__ X,
                                const float* __restrict__ W,
                                float* __restrict__ C,
                                const float* __restrict__ sc,
                                int M, int N, int K) {
    __shared__ float Xs[32][33];
    __shared__ float Ws[32][33];
    float speps = sc[1];
    int nbn = N / 32;
    int brow = (blockIdx.x / nbn) * 32;
    int bcol = (blockIdx.x % nbn) * 32;
    int tx = threadIdx.x & 31;
    int ty4 = threadIdx.x >> 5;
    float acc[4] = {0.f, 0.f, 0.f, 0.f};
    for (int kt = 0; kt < K; kt += 32) {
#pragma unroll
        for (int i = 0; i < 4; ++i) {
            int idx = threadIdx.x + i * 256;
            int r = idx >> 5, c = idx & 31;
            Xs[r][c] = X[(size_t)(brow + r) * K + kt + c];
            float wv = W[(size_t)(bcol + r) * K + kt + c];
            float t = wv / speps;
            t = fminf(fmaxf(t, -1.f), 1.f);
            Ws[r][c] = rintf(t);
        }
        __syncthreads();
#pragma unroll
        for (int kk = 0; kk < 32; ++kk) {
            float wv = Ws[tx][kk];
#pragma unroll
            for (int i = 0; i < 4; ++i) acc[i] += Xs[ty4 * 4 + i][kk] * wv;
        }
        __syncthreads();
    }
    float scale = sc[0];
#pragma unroll
    for (int i = 0; i < 4; ++i)
        C[(size_t)(brow + ty4 * 4 + i) * N + (bcol + tx)] = acc[i] * scale;
}

// ---------------------------------------------------------------------------
extern "C" void kernel_launch(void* const* d_in, const int* in_sizes, int n_in,
                              void* d_out, int out_size, void* d_ws,
                              size_t ws_size, hipStream_t stream) {
    const float* x = (const float*)d_in[0];   // [B,S,K] f32
    const float* w = (const float*)d_in[1];   // [N,K]   f32
    float* out = (float*)d_out;               // [B,S,N] f32

    const int K = 4096;
    const int N = 4096;
    int xn = in_sizes[0];                     // M*K
    int wn = in_sizes[1];                     // N*K
    int M = xn / K;

    const int NPART = 2048;
    size_t off_sc = (size_t)NPART * 8;
    size_t off_xb = off_sc + 64;
    size_t need = off_xb + ((size_t)xn + (size_t)wn) * 2;

    bool shape_ok = (M % 256 == 0) && (N % 256 == 0) && (K % 256 == 0);

    if (ws_size >= need && shape_ok) {
        double* partials = (double*)d_ws;
        float* sc = (float*)((char*)d_ws + off_sc);
        __hip_bfloat16* xb = (__hip_bfloat16*)((char*)d_ws + off_xb);
        __hip_bfloat16* wq = xb + xn;

        absmean_partial_k<<<NPART, 256, 0, stream>>>(w, partials);
        absmean_final_k<<<1, 256, 0, stream>>>(partials, sc, NPART, wn);
        quantize_w_k<<<wn / 2048, 256, 0, stream>>>(w, wq, sc);
        cast_x_k<<<xn / 2048, 256, 0, stream>>>(x, xb);

        hipFuncSetAttribute(reinterpret_cast<const void*>(gemm8_k),
                            hipFuncAttributeMaxDynamicSharedMemorySize, 131072);
        dim3 grid((M / 256) * (N / 256));
        gemm8_k<<<grid, 512, 131072, stream>>>(xb, wq, out, sc, M, N, K);
    } else {
        double* partials = (double*)d_out;
        float* sc = (float*)d_ws;
        absmean_partial_k<<<NPART, 256, 0, stream>>>(w, partials);
        absmean_final_k<<<1, 256, 0, stream>>>(partials, sc, NPART, wn);
        dim3 grid((M / 32) * (N / 32));
        gemm_fallback_k<<<grid, 256, 0, stream>>>(x, w, out, sc, M, N, K);
    }
}